// Round 10
// baseline (166.652 us; speedup 1.0000x reference)
//
#include <hip/hip_runtime.h>
#include <math.h>

#define WAVES_PER_BLOCK 4
#define BLOCK 256
#define TBL_STRIDE 128          // floats per depo in ws table (512 B, 16B-aligned)

typedef float f32x4 __attribute__((ext_vector_type(4)));
typedef float f32x2 __attribute__((ext_vector_type(2)));

// ---------- K1: compute per-depo weight tables -> ws; offsets -> out ----------
__global__ __launch_bounds__(BLOCK) void raster_tables(
    const float* __restrict__ sigma, const float* __restrict__ time_,
    const float* __restrict__ charge, const float* __restrict__ tail,
    const float* __restrict__ gsp,
    float* __restrict__ tbl, float* __restrict__ out_off, int n, int niter)
{
    const int wave = threadIdx.x >> 6;
    const int lane = threadIdx.x & 63;
    const int nwaves = gridDim.x * WAVES_PER_BLOCK;
    int d = blockIdx.x * WAVES_PER_BLOCK + wave;

    const float g0 = gsp[0], g1 = gsp[1], g2 = gsp[2];
    const int dim = lane / 11;            // lanes 0..10 dim0, 11..21 dim1, 22..32 dim2
    const int k   = lane - dim * 11;
    const float gdim = (dim == 0) ? g0 : (dim == 1) ? g1 : g2;

    // gather sources: w0[j] in lane j, w1[j] in lane 11+j, w2[j] in lane 22+j
    const int i0a = lane;
    const int s0a = i0a / 10, s1a = 11 + i0a % 10;
    const int i0b = lane + 64;
    const int s0b = i0b / 10, s1b = 11 + i0b % 10;

    for (int it = 0; it < niter; ++it, d += nwaves) {
        if (d >= n) break;                 // d uniform per wave

        float pt = 0.f, sg = 1.f;
        if (lane < 33) {
            pt = (dim == 0) ? tail[(size_t)d*3 + 1]
               : (dim == 1) ? tail[(size_t)d*3 + 2]
               : time_[d];
            sg = sigma[(size_t)d*3 + dim];
        }
        float q = charge[d];

        float cdf = 0.f, iminf = 0.f;
        if (lane < 33) {
            iminf = floorf((pt - 3.0f * sg) / gdim);
            float edge = (iminf + (float)k) * gdim;
            float z = (edge - pt) / (sg * 1.4142135623730951f);
            cdf = 0.5f * (1.0f + erff(z));
        }
        float cdf1 = __shfl_down(cdf, 1);
        float wv = cdf1 - cdf;             // valid where k<10

        if (lane < 33 && k == 0)
            out_off[(size_t)d*3 + dim] = iminf;

        float* t = tbl + (size_t)d * TBL_STRIDE;
        float w0a = __shfl(wv, s0a), w1a = __shfl(wv, s1a);
        t[i0a] = q * w0a * w1a;
        float w0b = __shfl(wv, s0b), w1b = __shfl(wv, s1b);
        if (i0b < 100) t[i0b] = q * w0b * w1b;
        if (lane >= 22 && lane < 32) t[104 + lane - 22] = wv;       // w2e[0..9]
        if (lane >= 22 && lane < 25) t[104 + lane - 22 + 10] = wv;  // w2e wrap [10..12]
    }
}

// ---------- K2: pure streamer — table -> LDS -> 4 KB store burst ----------
__global__ __launch_bounds__(BLOCK) void raster_store(
    const float* __restrict__ tbl, float* __restrict__ out_r, int n, int niter)
{
    __shared__ float s_tbl[WAVES_PER_BLOCK][2][120];   // double-buffered table slot

    const int wave = threadIdx.x >> 6;
    const int lane = threadIdx.x & 63;
    const int nwaves = gridDim.x * WAVES_PER_BLOCK;
    int d = blockIdx.x * WAVES_PER_BLOCK + wave;

    // loop-invariant chunk indices: c = lane+64cc, f = 4c; i2 = f%10 always even
    int  jc[4], i2c[4];
    bool on[4], cross[4];
    #pragma unroll
    for (int cc = 0; cc < 4; ++cc) {
        int c = lane + 64 * cc;
        on[cc]    = (c < 250);
        int f     = 4 * c;
        jc[cc]    = f / 10;
        i2c[cc]   = f % 10;
        cross[cc] = (i2c[cc] == 8);
    }

    // prologue: stage first depo's table (30 lanes x f32x4 = 120 floats)
    f32x4 t0 = {0.f, 0.f, 0.f, 0.f};
    if (lane < 30 && d < n)
        t0 = *reinterpret_cast<const f32x4*>(tbl + (size_t)d * TBL_STRIDE + lane * 4);
    if (lane < 30)
        *reinterpret_cast<f32x4*>(&s_tbl[wave][0][lane * 4]) = t0;

    for (int it = 0; it < niter; ++it) {
        const int cur = it & 1;
        const int dn  = d + nwaves;

        // prefetch next depo's table (latency hidden under store burst)
        f32x4 tn = {0.f, 0.f, 0.f, 0.f};
        if (lane < 30 && dn < n)
            tn = *reinterpret_cast<const f32x4*>(tbl + (size_t)dn * TBL_STRIDE + lane * 4);

        // store burst for current depo
        if (d < n) {
            const float* qw  = s_tbl[wave][cur];
            const float* w2e = qw + 104;
            float* base = out_r + (size_t)d * 1000;
            #pragma unroll
            for (int cc = 0; cc < 4; ++cc) {
                if (on[cc]) {
                    float a = qw[jc[cc]];
                    float b = qw[jc[cc] + 1];              // used only when cross
                    f32x2 wlo = *reinterpret_cast<const f32x2*>(&w2e[i2c[cc]]);
                    f32x2 whi = *reinterpret_cast<const f32x2*>(&w2e[i2c[cc] + 2]);
                    float qzw = cross[cc] ? b : a;
                    f32x4 v;
                    v.x = a   * wlo.x;
                    v.y = a   * wlo.y;
                    v.z = qzw * whi.x;
                    v.w = qzw * whi.y;
                    *reinterpret_cast<f32x4*>(base + 4 * (lane + 64 * cc)) = v;
                }
            }
        }

        // stage next table into the other slot (after the burst, wave-local order)
        if (lane < 30)
            *reinterpret_cast<f32x4*>(&s_tbl[wave][cur ^ 1][lane * 4]) = tn;

        d = dn;
    }
}

// ---------- fallback (R7 single-kernel) if ws too small ----------
__global__ __launch_bounds__(BLOCK) void raster_fused(
    const float* __restrict__ sigma, const float* __restrict__ time_,
    const float* __restrict__ charge, const float* __restrict__ tail,
    const float* __restrict__ gsp,
    float* __restrict__ out_r, float* __restrict__ out_off, int n, int niter)
{
    __shared__ float s_qw01[WAVES_PER_BLOCK][104];
    __shared__ float s_w2e [WAVES_PER_BLOCK][16];

    const int wave = threadIdx.x >> 6;
    const int lane = threadIdx.x & 63;
    const int nwaves = gridDim.x * WAVES_PER_BLOCK;
    int d = blockIdx.x * WAVES_PER_BLOCK + wave;

    const float g0 = gsp[0], g1 = gsp[1], g2 = gsp[2];
    const int dim = lane / 11;
    const int k   = lane - dim * 11;
    const float gdim = (dim == 0) ? g0 : (dim == 1) ? g1 : g2;

    const int i0a = lane;
    const int s0a = i0a / 10, s1a = 11 + i0a % 10;
    const int i0b = lane + 64;
    const int s0b = i0b / 10, s1b = 11 + i0b % 10;

    int  jc[4], i2c[4];
    bool on[4], cross[4];
    #pragma unroll
    for (int cc = 0; cc < 4; ++cc) {
        int c = lane + 64 * cc;
        on[cc]    = (c < 250);
        int f     = 4 * c;
        jc[cc]    = f / 10;
        i2c[cc]   = f % 10;
        cross[cc] = (i2c[cc] == 8);
    }

    const float* qw  = s_qw01[wave];
    const float* w2e = s_w2e[wave];

    for (int it = 0; it < niter; ++it, d += nwaves) {
        const bool active = (d < n);

        float pt = 0.f, sg = 1.f, q = 0.f;
        if (active) {
            if (lane < 33) {
                pt = (dim == 0) ? tail[(size_t)d*3 + 1]
                   : (dim == 1) ? tail[(size_t)d*3 + 2]
                   : time_[d];
                sg = sigma[(size_t)d*3 + dim];
            }
            q = charge[d];
        }

        float cdf = 0.f, iminf = 0.f;
        if (lane < 33) {
            iminf = floorf((pt - 3.0f * sg) / gdim);
            float edge = (iminf + (float)k) * gdim;
            float z = (edge - pt) / (sg * 1.4142135623730951f);
            cdf = 0.5f * (1.0f + erff(z));
        }
        float cdf1 = __shfl_down(cdf, 1);
        float wv = cdf1 - cdf;

        if (active && lane < 33 && k == 0)
            out_off[(size_t)d*3 + dim] = iminf;

        {
            float w0a = __shfl(wv, s0a), w1a = __shfl(wv, s1a);
            s_qw01[wave][i0a] = q * w0a * w1a;
            float w0b = __shfl(wv, s0b), w1b = __shfl(wv, s1b);
            if (i0b < 100) s_qw01[wave][i0b] = q * w0b * w1b;
            if (lane >= 22 && lane < 32) s_w2e[wave][lane - 22] = wv;
            if (lane >= 22 && lane < 25) s_w2e[wave][lane - 22 + 10] = wv;
        }

        if (active) {
            float* base = out_r + (size_t)d * 1000;
            #pragma unroll
            for (int cc = 0; cc < 4; ++cc) {
                if (on[cc]) {
                    float a = qw[jc[cc]];
                    float b = qw[jc[cc] + 1];
                    f32x2 wlo = *reinterpret_cast<const f32x2*>(&w2e[i2c[cc]]);
                    f32x2 whi = *reinterpret_cast<const f32x2*>(&w2e[i2c[cc] + 2]);
                    float qzw = cross[cc] ? b : a;
                    f32x4 v;
                    v.x = a   * wlo.x;
                    v.y = a   * wlo.y;
                    v.z = qzw * whi.x;
                    v.w = qzw * whi.y;
                    *reinterpret_cast<f32x4*>(base + 4 * (lane + 64 * cc)) = v;
                }
            }
        }
    }
}

extern "C" void kernel_launch(void* const* d_in, const int* in_sizes, int n_in,
                              void* d_out, int out_size, void* d_ws, size_t ws_size,
                              hipStream_t stream) {
    const float* sigma  = (const float*)d_in[0];
    const float* time_  = (const float*)d_in[1];
    const float* charge = (const float*)d_in[2];
    const float* tail   = (const float*)d_in[3];
    const float* gsp    = (const float*)d_in[4];

    const int n = in_sizes[1];          // N depos (time is [N])
    float* out_r   = (float*)d_out;
    float* out_off = out_r + (size_t)n * 1000;

    const int blocks = 4096;
    const int nwaves = blocks * WAVES_PER_BLOCK;        // 16384
    const int niter  = (n + nwaves - 1) / nwaves;       // 8 at N=131072

    const size_t need = (size_t)n * TBL_STRIDE * sizeof(float);   // 67 MB
    if (ws_size >= need) {
        float* tbl = (float*)d_ws;
        raster_tables<<<blocks, BLOCK, 0, stream>>>(sigma, time_, charge, tail, gsp,
                                                    tbl, out_off, n, niter);
        raster_store <<<blocks, BLOCK, 0, stream>>>(tbl, out_r, n, niter);
    } else {
        raster_fused <<<blocks, BLOCK, 0, stream>>>(sigma, time_, charge, tail, gsp,
                                                    out_r, out_off, n, niter);
    }
}

// Round 11
// 156.420 us; speedup vs baseline: 1.0654x; 1.0654x over previous
//
#include <hip/hip_runtime.h>
#include <math.h>

#define WAVES_PER_BLOCK 4
#define BLOCK 256
#define TBL_STRIDE 32           // floats per depo: w0[10] w1[10] w2[10] q pad

typedef float f32x4 __attribute__((ext_vector_type(4)));
typedef float f32x2 __attribute__((ext_vector_type(2)));

// ---------- K1: compute compact per-depo tables (32 floats) -> ws ----------
__global__ __launch_bounds__(BLOCK) void raster_tables(
    const float* __restrict__ sigma, const float* __restrict__ time_,
    const float* __restrict__ charge, const float* __restrict__ tail,
    const float* __restrict__ gsp,
    float* __restrict__ tbl, float* __restrict__ out_off, int n, int niter)
{
    const int lane = threadIdx.x & 63;
    const int wave = threadIdx.x >> 6;
    const int nwaves = gridDim.x * WAVES_PER_BLOCK;
    int d = blockIdx.x * WAVES_PER_BLOCK + wave;

    const float g0 = gsp[0], g1 = gsp[1], g2 = gsp[2];
    const int dim = lane / 11;            // lanes 0..10 dim0, 11..21 dim1, 22..32 dim2
    const int k   = lane - dim * 11;
    const float gdim = (dim == 0) ? g0 : (dim == 1) ? g1 : g2;

    // table gather source: t[j] j<10 -> wv lane j; 10..19 -> lane j+1; 20..29 -> lane j+2
    const int gsrc = (lane < 10) ? lane : (lane < 20) ? lane + 1
                   : (lane < 30) ? lane + 2 : 0;

    for (int it = 0; it < niter; ++it, d += nwaves) {
        if (d >= n) break;                 // d uniform per wave

        float pt = 0.f, sg = 1.f;
        if (lane < 33) {
            pt = (dim == 0) ? tail[(size_t)d*3 + 1]
               : (dim == 1) ? tail[(size_t)d*3 + 2]
               : time_[d];
            sg = sigma[(size_t)d*3 + dim];
        }
        float q = charge[d];

        float cdf = 0.f, iminf = 0.f;
        if (lane < 33) {
            iminf = floorf((pt - 3.0f * sg) / gdim);
            float edge = (iminf + (float)k) * gdim;
            float z = (edge - pt) / (sg * 1.4142135623730951f);
            cdf = 0.5f * (1.0f + erff(z));
        }
        float cdf1 = __shfl_down(cdf, 1);
        float wv = cdf1 - cdf;             // valid where k<10

        if (lane < 33 && k == 0)
            out_off[(size_t)d*3 + dim] = iminf;

        float val = __shfl(wv, gsrc);
        if (lane == 30) val = q;
        if (lane == 31) val = 0.f;
        if (lane < 32) tbl[(size_t)d * TBL_STRIDE + lane] = val;   // one 128B line
    }
}

// ---------- K2: fill-clone streamer — 1 line read -> shuffles -> 4KB burst ----------
__global__ __launch_bounds__(BLOCK) void raster_store(
    const float* __restrict__ tbl, float* __restrict__ out_r, int n, int ndepo)
{
    const int lane = threadIdx.x & 63;
    const int wave = threadIdx.x >> 6;
    const int wid  = blockIdx.x * WAVES_PER_BLOCK + wave;

    int d = wid * ndepo;                       // contiguous 256KB sweep per wave
    const int dend = min(d + ndepo, n);

    // loop-invariant per-chunk shuffle sources: c = lane+64cc, f = 4c
    // table layout: w0 at [0..9], w1 at [10..19], w2 at [20..29], q at [30]
    int sw0lo[4], sw1lo[4], sw0hi[4], sw1hi[4], s2a[4], s2b[4], s2c[4], s2d[4];
    bool on[4];
    #pragma unroll
    for (int cc = 0; cc < 4; ++cc) {
        int c  = lane + 64 * cc;
        on[cc] = (c < 250);
        int f  = 4 * c;
        int j0 = (f / 10) % 100;          // qw index for elements 0,1
        int j1 = ((f + 2) / 10) % 100;    // qw index for elements 2,3
        int i2 = f % 10;                  // always even
        sw0lo[cc] = j0 / 10;  sw1lo[cc] = 10 + j0 % 10;
        sw0hi[cc] = j1 / 10;  sw1hi[cc] = 10 + j1 % 10;
        s2a[cc] = 20 + i2;
        s2b[cc] = 20 + i2 + 1;
        s2c[cc] = 20 + (i2 + 2) % 10;
        s2d[cc] = 20 + (i2 + 3) % 10;
    }

    // prologue: load first depo's table line (coalesced 128B)
    float tv = 0.f;
    if (lane < 32 && d < dend)
        tv = tbl[(size_t)d * TBL_STRIDE + lane];

    for (; d < dend; ++d) {
        const int dn = d + 1;

        // depth-1 prefetch of next table line (hidden under store burst)
        float tvn = 0.f;
        if (lane < 32 && dn < dend)
            tvn = tbl[(size_t)dn * TBL_STRIDE + lane];

        const float q = __shfl(tv, 30);

        // compute all 16 output values in registers (no LDS)
        f32x4 v[4];
        #pragma unroll
        for (int cc = 0; cc < 4; ++cc) {
            float w0lo = __shfl(tv, sw0lo[cc]);
            float w1lo = __shfl(tv, sw1lo[cc]);
            float w0hi = __shfl(tv, sw0hi[cc]);
            float w1hi = __shfl(tv, sw1hi[cc]);
            float w2a  = __shfl(tv, s2a[cc]);
            float w2b  = __shfl(tv, s2b[cc]);
            float w2c  = __shfl(tv, s2c[cc]);
            float w2d  = __shfl(tv, s2d[cc]);
            float a = q * w0lo * w1lo;
            float b = q * w0hi * w1hi;
            v[cc].x = a * w2a;
            v[cc].y = a * w2b;
            v[cc].z = b * w2c;
            v[cc].w = b * w2d;
        }

        // pure 4KB store burst, back-to-back
        float* base = out_r + (size_t)d * 1000;
        *reinterpret_cast<f32x4*>(base + 4 * lane)         = v[0];
        *reinterpret_cast<f32x4*>(base + 4 * (lane + 64))  = v[1];
        *reinterpret_cast<f32x4*>(base + 4 * (lane + 128)) = v[2];
        if (on[3])
            *reinterpret_cast<f32x4*>(base + 4 * (lane + 192)) = v[3];

        tv = tvn;
    }
}

// ---------- fallback (fused single-kernel) if ws too small ----------
__global__ __launch_bounds__(BLOCK) void raster_fused(
    const float* __restrict__ sigma, const float* __restrict__ time_,
    const float* __restrict__ charge, const float* __restrict__ tail,
    const float* __restrict__ gsp,
    float* __restrict__ out_r, float* __restrict__ out_off, int n, int niter)
{
    __shared__ float s_qw01[WAVES_PER_BLOCK][104];
    __shared__ float s_w2e [WAVES_PER_BLOCK][16];

    const int wave = threadIdx.x >> 6;
    const int lane = threadIdx.x & 63;
    const int nwaves = gridDim.x * WAVES_PER_BLOCK;
    int d = blockIdx.x * WAVES_PER_BLOCK + wave;

    const float g0 = gsp[0], g1 = gsp[1], g2 = gsp[2];
    const int dim = lane / 11;
    const int k   = lane - dim * 11;
    const float gdim = (dim == 0) ? g0 : (dim == 1) ? g1 : g2;

    const int i0a = lane;
    const int s0a = i0a / 10, s1a = 11 + i0a % 10;
    const int i0b = lane + 64;
    const int s0b = i0b / 10, s1b = 11 + i0b % 10;

    int  jc[4], i2c[4];
    bool on[4], cross[4];
    #pragma unroll
    for (int cc = 0; cc < 4; ++cc) {
        int c = lane + 64 * cc;
        on[cc]    = (c < 250);
        int f     = 4 * c;
        jc[cc]    = f / 10;
        i2c[cc]   = f % 10;
        cross[cc] = (i2c[cc] == 8);
    }

    const float* qw  = s_qw01[wave];
    const float* w2e = s_w2e[wave];

    for (int it = 0; it < niter; ++it, d += nwaves) {
        const bool active = (d < n);

        float pt = 0.f, sg = 1.f, q = 0.f;
        if (active) {
            if (lane < 33) {
                pt = (dim == 0) ? tail[(size_t)d*3 + 1]
                   : (dim == 1) ? tail[(size_t)d*3 + 2]
                   : time_[d];
                sg = sigma[(size_t)d*3 + dim];
            }
            q = charge[d];
        }

        float cdf = 0.f, iminf = 0.f;
        if (lane < 33) {
            iminf = floorf((pt - 3.0f * sg) / gdim);
            float edge = (iminf + (float)k) * gdim;
            float z = (edge - pt) / (sg * 1.4142135623730951f);
            cdf = 0.5f * (1.0f + erff(z));
        }
        float cdf1 = __shfl_down(cdf, 1);
        float wv = cdf1 - cdf;

        if (active && lane < 33 && k == 0)
            out_off[(size_t)d*3 + dim] = iminf;

        {
            float w0a = __shfl(wv, s0a), w1a = __shfl(wv, s1a);
            s_qw01[wave][i0a] = q * w0a * w1a;
            float w0b = __shfl(wv, s0b), w1b = __shfl(wv, s1b);
            if (i0b < 100) s_qw01[wave][i0b] = q * w0b * w1b;
            if (lane >= 22 && lane < 32) s_w2e[wave][lane - 22] = wv;
            if (lane >= 22 && lane < 25) s_w2e[wave][lane - 22 + 10] = wv;
        }

        if (active) {
            float* base = out_r + (size_t)d * 1000;
            #pragma unroll
            for (int cc = 0; cc < 4; ++cc) {
                if (on[cc]) {
                    float a = qw[jc[cc]];
                    float b = qw[jc[cc] + 1];
                    f32x2 wlo = *reinterpret_cast<const f32x2*>(&w2e[i2c[cc]]);
                    f32x2 whi = *reinterpret_cast<const f32x2*>(&w2e[i2c[cc] + 2]);
                    float qzw = cross[cc] ? b : a;
                    f32x4 v;
                    v.x = a   * wlo.x;
                    v.y = a   * wlo.y;
                    v.z = qzw * whi.x;
                    v.w = qzw * whi.y;
                    *reinterpret_cast<f32x4*>(base + 4 * (lane + 64 * cc)) = v;
                }
            }
        }
    }
}

extern "C" void kernel_launch(void* const* d_in, const int* in_sizes, int n_in,
                              void* d_out, int out_size, void* d_ws, size_t ws_size,
                              hipStream_t stream) {
    const float* sigma  = (const float*)d_in[0];
    const float* time_  = (const float*)d_in[1];
    const float* charge = (const float*)d_in[2];
    const float* tail   = (const float*)d_in[3];
    const float* gsp    = (const float*)d_in[4];

    const int n = in_sizes[1];          // N depos (time is [N])
    float* out_r   = (float*)d_out;
    float* out_off = out_r + (size_t)n * 1000;

    const size_t need = (size_t)n * TBL_STRIDE * sizeof(float);   // 16.8 MB
    if (ws_size >= need) {
        float* tbl = (float*)d_ws;
        // K1: latency-bound -> full occupancy, grid-stride
        {
            const int blocks = 4096;
            const int nwaves = blocks * WAVES_PER_BLOCK;
            const int niter  = (n + nwaves - 1) / nwaves;
            raster_tables<<<blocks, BLOCK, 0, stream>>>(sigma, time_, charge, tail,
                                                        gsp, tbl, out_off, n, niter);
        }
        // K2: fill-clone -> low occupancy, contiguous 64-depo sweeps per wave
        {
            const int blocks = 512;                       // 2048 waves
            const int nwaves = blocks * WAVES_PER_BLOCK;
            const int ndepo  = (n + nwaves - 1) / nwaves; // 64 at N=131072
            raster_store<<<blocks, BLOCK, 0, stream>>>(tbl, out_r, n, ndepo);
        }
    } else {
        const int blocks = 4096;
        const int nwaves = blocks * WAVES_PER_BLOCK;
        const int niter  = (n + nwaves - 1) / nwaves;
        raster_fused<<<blocks, BLOCK, 0, stream>>>(sigma, time_, charge, tail, gsp,
                                                   out_r, out_off, n, niter);
    }
}